// Round 11
// baseline (1381.325 us; speedup 1.0000x reference)
//
#include <hip/hip_runtime.h>
#include <hip/hip_bf16.h>

typedef __hip_bfloat16 bf16;
typedef unsigned int u32;
typedef __attribute__((ext_vector_type(8))) short short8v;   // 8 bf16 = 4 VGPRs (MFMA A/B frag)
typedef __attribute__((ext_vector_type(4))) float f32x4;     // MFMA C/D frag

__device__ __forceinline__ float lrelu_f(float v) { return v > 0.f ? v : 0.01f * v; }
__device__ __forceinline__ float bf_lo(u32 u) { return __uint_as_float(u << 16); }
__device__ __forceinline__ float bf_hi(u32 u) { return __uint_as_float(u & 0xffff0000u); }
__device__ __forceinline__ unsigned short bbits(float v) {
    union { bf16 b; unsigned short s; } u; u.b = __float2bfloat16(v); return u.s;
}
__device__ __forceinline__ u32 pack2(float a, float b) {
    return (u32)bbits(a) | ((u32)bbits(b) << 16);
}
__device__ __forceinline__ float ld_ext(const void* p, size_t idx, int f32f) {
    return f32f ? ((const float*)p)[idx] : __bfloat162float(((const bf16*)p)[idx]);
}

// flags[0]: ei int64? flags[1]: batch int64? flags[2]: floats f32?  Also inits identity affine.
__global__ void probe_k(const int* __restrict__ ei, const int* __restrict__ batch,
                        const u32* __restrict__ bng, int nedges, int nnodes,
                        int* __restrict__ flags, float* __restrict__ scaleA,
                        float* __restrict__ shiftA)
{
    __shared__ int nz[2];
    if (threadIdx.x < 2) nz[threadIdx.x] = 0;
    __syncthreads();
    int t = threadIdx.x;
    if (ei[(nedges + 2 * t) | 1] != 0) atomicAdd(&nz[0], 1);
    if (batch[((nnodes >> 1) + 2 * t) | 1] != 0) atomicAdd(&nz[1], 1);
    if (t < 128) { scaleA[t] = 1.f; shiftA[t] = 0.f; }
    __syncthreads();
    if (t == 0) {
        flags[0] = (nz[0] == 0) ? 1 : 0;
        flags[1] = (nz[1] == 0) ? 1 : 0;
        flags[2] = (bng[0] == 0x3F800000u) ? 1 : 0;
    }
}

// ---------------- CSR build ----------------
__global__ __launch_bounds__(256)
void hist_k(const int* __restrict__ ei, int* __restrict__ deg, int nedges,
            const int* __restrict__ flags)
{
    int e = blockIdx.x * 256 + threadIdx.x;
    if (e >= nedges) return;
    int f = flags[0];
    int dst = f ? ei[(nedges + e) << 1] : ei[nedges + e];
    atomicAdd(&deg[dst], 1);
}

__global__ __launch_bounds__(256)
void scan1_k(const int* __restrict__ deg, int* __restrict__ bsum, int n)
{
    __shared__ int l[256];
    int t = threadIdx.x, i = blockIdx.x * 256 + t;
    l[t] = (i < n) ? deg[i] : 0;
    __syncthreads();
    for (int off = 128; off > 0; off >>= 1) {
        if (t < off) l[t] += l[t + off];
        __syncthreads();
    }
    if (t == 0) bsum[blockIdx.x] = l[0];
}
__global__ __launch_bounds__(1024)
void scan2_k(int* __restrict__ bsum, int nb)
{
    __shared__ int l[1024];
    int t = threadIdx.x;
    int orig = (t < nb) ? bsum[t] : 0;
    l[t] = orig;
    __syncthreads();
    for (int off = 1; off < 1024; off <<= 1) {
        int v = (t >= off) ? l[t - off] : 0;
        __syncthreads();
        l[t] += v;
        __syncthreads();
    }
    if (t < nb) bsum[t] = l[t] - orig;
}
__global__ __launch_bounds__(256)
void scan3_k(const int* __restrict__ deg, const int* __restrict__ bsum,
             int* __restrict__ rowptr, int* __restrict__ cursor, int n)
{
    __shared__ int l[256];
    int t = threadIdx.x, i = blockIdx.x * 256 + t;
    int d = (i < n) ? deg[i] : 0;
    l[t] = d;
    __syncthreads();
    for (int off = 1; off < 256; off <<= 1) {
        int v = (t >= off) ? l[t - off] : 0;
        __syncthreads();
        l[t] += v;
        __syncthreads();
    }
    int excl = l[t] - d + bsum[blockIdx.x];
    if (i < n) {
        rowptr[i] = excl;
        cursor[i] = excl;
        if (i == n - 1) rowptr[n] = excl + d;
    }
}

__global__ __launch_bounds__(256)
void fill_k(const int* __restrict__ ei, int* __restrict__ cursor,
            int* __restrict__ srcs, int nedges, const int* __restrict__ flags)
{
    int e = blockIdx.x * 256 + threadIdx.x;
    if (e >= nedges) return;
    int f = flags[0];
    int src = ei[e << f];
    int dst = f ? ei[(nedges + e) << 1] : ei[nedges + e];
    int pos = atomicAdd(&cursor[dst], 1);
    srcs[pos] = src;
}

// ---------------- consolidated weight prep (all tensors, one launch) ----------------
__global__ __launch_bounds__(256)
void wprep_all_k(const void* __restrict__ pre_w, const void* __restrict__ w1,
                 const void* __restrict__ w2, const void* __restrict__ f0,
                 const void* __restrict__ f1, const void* __restrict__ f2,
                 const void* __restrict__ f3, bf16* __restrict__ Wf,
                 const int* __restrict__ flags)
{
    int e = blockIdx.x * 256 + threadIdx.x;
    if (e >= 1196032) return;
    const void* W; int K, wstride, l, r;
    if (e < 16384)       { W = pre_w; K = 128; wstride = 128; l = 0; r = e; }
    else if (e < 81920)  { int q = e - 16384; W = w1; K = 128; wstride = 128; l = q >> 14; r = q & 16383; }
    else if (e < 147456) { int q = e - 81920; W = w2; K = 128; wstride = 128; l = q >> 14; r = q & 16383; }
    else {
        int q = e - 147456; int m = q >> 18; r = q & 262143;
        W = (m == 0) ? f0 : (m == 1) ? f1 : (m == 2) ? f2 : f3;
        K = 512; wstride = 512; l = 0;
    }
    int KS = K >> 5;
    int j = r & 7, lane = (r >> 3) & 63;
    int rem = r >> 9;
    int ks = rem % KS, nt = rem / KS;
    int k = ks * 32 + ((lane >> 4) << 3) + j;
    int n = nt * 16 + (lane & 15);
    Wf[e] = __float2bfloat16(ld_ext(W, (size_t)(l * K + k) * wstride + n, flags[2]));
}

// ---------------- MFMA GEMM (FF head): out = act(A @ W (+bias)) ----------------
template<int SRC, int MODE, int OBF>
__global__ __launch_bounds__(256)
void mgemm_k(const void* __restrict__ A, const bf16* __restrict__ Wf,
             const void* __restrict__ bias, void* __restrict__ out,
             int nrows, int K, int astride, int ostride, const int* __restrict__ flags)
{
    const int KS = K >> 5;
    const int t = threadIdx.x, w = t >> 6, lane = t & 63;
    const int quad = lane >> 4, lr = lane & 15;
    const int rbase = blockIdx.x * 64 + w * 16;
    const int arow = min(rbase + lr, nrows - 1);
    const int ntg0 = blockIdx.y * 8;
    const int f32f = flags[2];

    f32x4 acc[8];
    #pragma unroll
    for (int i = 0; i < 8; ++i) acc[i] = (f32x4){0.f, 0.f, 0.f, 0.f};

    for (int ks = 0; ks < KS; ++ks) {
        const int kof = ks * 32 + quad * 8;
        short8v a;
        if (SRC == 0 || f32f) {
            const float* Af = (const float*)A + (size_t)arow * astride + kof;
            float4 p0 = *(const float4*)Af;
            float4 p1 = *(const float4*)(Af + 4);
            a[0] = (short)bbits(p0.x); a[1] = (short)bbits(p0.y);
            a[2] = (short)bbits(p0.z); a[3] = (short)bbits(p0.w);
            a[4] = (short)bbits(p1.x); a[5] = (short)bbits(p1.y);
            a[6] = (short)bbits(p1.z); a[7] = (short)bbits(p1.w);
        } else {
            a = *(const short8v*)((const short*)A + (size_t)arow * astride + kof);
        }
        #pragma unroll
        for (int nt = 0; nt < 8; ++nt) {
            const short8v b = *(const short8v*)&Wf[(((size_t)(ntg0 + nt) * KS + ks) * 64 + lane) * 8];
            acc[nt] = __builtin_amdgcn_mfma_f32_16x16x32_bf16(a, b, acc[nt], 0, 0, 0);
        }
    }

    #pragma unroll
    for (int nt = 0; nt < 8; ++nt) {
        const int col = (ntg0 + nt) * 16 + lr;
        float bv = 0.f;
        if (MODE == 0 && bias != nullptr) bv = ld_ext(bias, col, f32f);
        #pragma unroll
        for (int r = 0; r < 4; ++r) {
            int orow = rbase + quad * 4 + r;
            if (orow < nrows) {
                float v = acc[nt][r] + bv;
                if (MODE == 1) v = lrelu_f(v);
                if (OBF) ((bf16*)out)[(size_t)orow * ostride + col] = __float2bfloat16(v);
                else     ((float*)out)[(size_t)orow * ostride + col] = v;
            }
        }
    }
}

// ---------------- persistent pre-projection: h = bf16(x @ pre_w + pre_b) ----------------
// Transposed operands: h^T = W^T · x^T. Wave-pair per 16-node tile; wave hw owns 64 channels.
// Weight frags (64 VGPRs) + bias pinned in registers via asm anti-remat. No LDS, no barriers.
__global__ __launch_bounds__(256, 2)
void pre_k(const void* __restrict__ x, const bf16* __restrict__ Wf,
           const void* __restrict__ bias, u32* __restrict__ h,
           int nrows, int ntiles, int npairs, const int* __restrict__ flags)
{
    const int t = threadIdx.x, w = t >> 6, lane = t & 63;
    const int quad = lane >> 4, lr = lane & 15;
    const int gpair = blockIdx.x * 2 + (w >> 1);
    const int hw = w & 1;
    const int chb = hw * 64;
    const int f32f = flags[2];

    short8v wf[4][4];
    #pragma unroll
    for (int i = 0; i < 4; ++i)
        #pragma unroll
        for (int ks = 0; ks < 4; ++ks) {
            wf[i][ks] = *(const short8v*)&Wf[(((hw * 4 + i) * 4 + ks) * 64 + lane) * 8];
            asm volatile("" : "+v"(wf[i][ks]));
        }
    float bv[4][4];
    #pragma unroll
    for (int i = 0; i < 4; ++i)
        #pragma unroll
        for (int r = 0; r < 4; ++r)
            bv[i][r] = ld_ext(bias, chb + i * 16 + quad * 4 + r, f32f);

    const int iters = (ntiles + npairs - 1) / npairs;
    for (int it = 0; it < iters; ++it) {
        const int tile = gpair + it * npairs;
        if (tile >= ntiles) break;
        const int nodeu = tile * 16 + lr;
        const int node = min(nodeu, nrows - 1);

        f32x4 acc[4];
        #pragma unroll
        for (int i = 0; i < 4; ++i) acc[i] = (f32x4){0,0,0,0};
        #pragma unroll
        for (int ks = 0; ks < 4; ++ks) {
            short8v bfrag;
            if (f32f) {
                const float* xp = (const float*)x + (size_t)node * 128 + ks * 32 + quad * 8;
                float4 p0 = *(const float4*)xp;
                float4 p1 = *(const float4*)(xp + 4);
                bfrag[0] = (short)bbits(p0.x); bfrag[1] = (short)bbits(p0.y);
                bfrag[2] = (short)bbits(p0.z); bfrag[3] = (short)bbits(p0.w);
                bfrag[4] = (short)bbits(p1.x); bfrag[5] = (short)bbits(p1.y);
                bfrag[6] = (short)bbits(p1.z); bfrag[7] = (short)bbits(p1.w);
            } else {
                bfrag = *(const short8v*)((const short*)x + (size_t)node * 128 + ks * 32 + quad * 8);
            }
            #pragma unroll
            for (int i = 0; i < 4; ++i)
                acc[i] = __builtin_amdgcn_mfma_f32_16x16x32_bf16(wf[i][ks], bfrag, acc[i], 0, 0, 0);
        }
        if (nodeu < nrows) {
            #pragma unroll
            for (int i = 0; i < 4; ++i) {
                uint2 o;
                o.x = pack2(acc[i][0] + bv[i][0], acc[i][1] + bv[i][1]);
                o.y = pack2(acc[i][2] + bv[i][2], acc[i][3] + bv[i][3]);
                *(uint2*)&h[(size_t)nodeu * 64 + (chb >> 1) + i * 8 + quad * 2] = o;
            }
        }
    }
}

// ---------------- persistent fused GIN conv (out-of-place) ----------------
// stage1 P^T = W1^T·agg^T, stage2 h2^T = W2^T·P. Wave-pair per tile, wave hw owns 64 ch.
// W1+W2 frags (128 VGPRs) pinned via asm anti-remat; aggb prefetch double-buffered.
// BN stats accumulated via LDS atomics per iteration (saves 32 VGPRs).
__global__ __launch_bounds__(256, 2)
void conv_k(const u32* __restrict__ aggb, const bf16* __restrict__ Wf1,
            const bf16* __restrict__ Wf2, u32* __restrict__ h2,
            float* __restrict__ psum, float* __restrict__ psq,
            int nrows, int ntiles, int npairs)
{
    __shared__ bf16 PT[2][16][136];
    __shared__ float sblk[128], qblk[128];
    const int t = threadIdx.x, w = t >> 6, lane = t & 63;
    const int quad = lane >> 4, lr = lane & 15;
    const int pair = w >> 1, hw = w & 1;
    const int gpair = blockIdx.x * 2 + pair;
    const int chb = hw * 64;

    short8v w1f[4][4], w2f[4][4];
    #pragma unroll
    for (int i = 0; i < 4; ++i)
        #pragma unroll
        for (int ks = 0; ks < 4; ++ks) {
            int ntb = hw * 4 + i;
            w1f[i][ks] = *(const short8v*)&Wf1[((ntb * 4 + ks) * 64 + lane) * 8];
            w2f[i][ks] = *(const short8v*)&Wf2[((ntb * 4 + ks) * 64 + lane) * 8];
            asm volatile("" : "+v"(w1f[i][ks]));
            asm volatile("" : "+v"(w2f[i][ks]));
        }

    if (t < 128) { sblk[t] = 0.f; qblk[t] = 0.f; }
    __syncthreads();

    // prefetch first tile
    int tileC = gpair;
    bool actC = tileC < ntiles;
    int nodeuC = tileC * 16 + lr;
    short8v bcur[4];
    if (actC) {
        int nd = min(nodeuC, nrows - 1);
        #pragma unroll
        for (int ks = 0; ks < 4; ++ks)
            bcur[ks] = *(const short8v*)&aggb[(size_t)nd * 64 + ks * 16 + quad * 4];
    }

    const int iters = (ntiles + npairs - 1) / npairs;
    for (int it = 0; it < iters; ++it) {
        // prefetch next tile while computing current
        const int tileN = tileC + npairs;
        const bool actN = tileN < ntiles;
        short8v bnxt[4];
        if (actN) {
            int ndN = min(tileN * 16 + lr, nrows - 1);
            #pragma unroll
            for (int ks = 0; ks < 4; ++ks)
                bnxt[ks] = *(const short8v*)&aggb[(size_t)ndN * 64 + ks * 16 + quad * 4];
        }

        if (actC) {
            f32x4 acc[4];
            #pragma unroll
            for (int i = 0; i < 4; ++i) acc[i] = (f32x4){0,0,0,0};
            #pragma unroll
            for (int ks = 0; ks < 4; ++ks)
                #pragma unroll
                for (int i = 0; i < 4; ++i)
                    acc[i] = __builtin_amdgcn_mfma_f32_16x16x32_bf16(w1f[i][ks], bcur[ks], acc[i], 0, 0, 0);
            #pragma unroll
            for (int i = 0; i < 4; ++i) {
                uint2 p;
                p.x = pack2(lrelu_f(acc[i][0]), lrelu_f(acc[i][1]));
                p.y = pack2(lrelu_f(acc[i][2]), lrelu_f(acc[i][3]));
                *(uint2*)&PT[pair][lr][chb + i * 16 + quad * 4] = p;
            }
        }
        __syncthreads();
        if (actC) {
            f32x4 acc2[4];
            #pragma unroll
            for (int i = 0; i < 4; ++i) acc2[i] = (f32x4){0,0,0,0};
            #pragma unroll
            for (int ks = 0; ks < 4; ++ks) {
                const short8v pfrag = *(const short8v*)&PT[pair][lr][ks * 32 + quad * 8];
                #pragma unroll
                for (int i = 0; i < 4; ++i)
                    acc2[i] = __builtin_amdgcn_mfma_f32_16x16x32_bf16(w2f[i][ks], pfrag, acc2[i], 0, 0, 0);
            }
            if (nodeuC < nrows) {
                #pragma unroll
                for (int i = 0; i < 4; ++i) {
                    uint2 o;
                    o.x = pack2(acc2[i][0], acc2[i][1]);
                    o.y = pack2(acc2[i][2], acc2[i][3]);
                    *(uint2*)&h2[(size_t)nodeuC * 64 + (chb >> 1) + i * 8 + quad * 2] = o;
                    #pragma unroll
                    for (int r = 0; r < 4; ++r) {
                        float v = acc2[i][r];
                        atomicAdd(&sblk[chb + i * 16 + quad * 4 + r], v);
                        atomicAdd(&qblk[chb + i * 16 + quad * 4 + r], v * v);
                    }
                }
            }
        }
        __syncthreads();
        tileC = tileN; actC = actN; nodeuC = tileN * 16 + lr;
        #pragma unroll
        for (int ks = 0; ks < 4; ++ks) bcur[ks] = bnxt[ks];
    }

    if (t < 128) {
        psum[(size_t)blockIdx.x * 128 + t] = sblk[t];
        psq[(size_t)blockIdx.x * 128 + t] = qblk[t];
    }
}

// Column reduce of partials + BN scale/shift (one block per column).
__global__ __launch_bounds__(256)
void reduce_bn_k(const float* __restrict__ psum, const float* __restrict__ psq,
                 const void* __restrict__ g, const void* __restrict__ b,
                 float* __restrict__ scale, float* __restrict__ shift,
                 float inv_n, int layer, int nblk, const int* __restrict__ flags)
{
    __shared__ float ls[256], lq[256];
    int c = blockIdx.x, t = threadIdx.x;
    float s = 0.f, q = 0.f;
    for (int i = t; i < nblk; i += 256) {
        s += psum[(size_t)i * 128 + c];
        q += psq[(size_t)i * 128 + c];
    }
    ls[t] = s; lq[t] = q;
    __syncthreads();
    for (int off = 128; off > 0; off >>= 1) {
        if (t < off) { ls[t] += ls[t + off]; lq[t] += lq[t + off]; }
        __syncthreads();
    }
    if (t == 0) {
        int f32f = flags[2];
        size_t off = (size_t)layer * 128 + c;
        float mean = ls[0] * inv_n;
        float var = lq[0] * inv_n - mean * mean;
        float sc = ld_ext(g, off, f32f) * rsqrtf(fmaxf(var, 0.f) + 1e-4f);
        scale[c] = sc;
        shift[c] = ld_ext(b, off, f32f) - mean * sc;
    }
}

// Pull aggregate with BN affine folded: aggb[d] = scale*(sum of k raw h2 vals) + shift*k.
__global__ __launch_bounds__(256)
void aggregate_k(const int* __restrict__ rowptr, const int* __restrict__ srcs,
                 const u32* __restrict__ h2, u32* __restrict__ aggb,
                 const float* __restrict__ scale, const float* __restrict__ shift, int nnodes)
{
    int node = blockIdx.x * 4 + (threadIdx.x >> 6);
    if (node >= nnodes) return;
    int lane = threadIdx.x & 63;
    u32 u = h2[(size_t)node * 64 + lane];
    float ax = bf_lo(u), ay = bf_hi(u);
    int lo = rowptr[node], hi = rowptr[node + 1];
    int e = lo;
    for (; e + 4 <= hi; e += 4) {
        int s0 = srcs[e], s1 = srcs[e + 1], s2 = srcs[e + 2], s3 = srcs[e + 3];
        u32 v0 = h2[(size_t)s0 * 64 + lane];
        u32 v1 = h2[(size_t)s1 * 64 + lane];
        u32 v2 = h2[(size_t)s2 * 64 + lane];
        u32 v3 = h2[(size_t)s3 * 64 + lane];
        ax += bf_lo(v0) + bf_lo(v1) + bf_lo(v2) + bf_lo(v3);
        ay += bf_hi(v0) + bf_hi(v1) + bf_hi(v2) + bf_hi(v3);
    }
    for (; e < hi; ++e) {
        u32 v = h2[(size_t)srcs[e] * 64 + lane];
        ax += bf_lo(v);
        ay += bf_hi(v);
    }
    float cnt = (float)(hi - lo + 1);
    int c = lane * 2;
    float r0 = fmaf(ax, scale[c], shift[c] * cnt);
    float r1 = fmaf(ay, scale[c + 1], shift[c + 1] * cnt);
    aggb[(size_t)node * 64 + lane] = pack2(r0, r1);
}

__device__ __forceinline__ int lower_bound_b(const int* b, int n, int key, int fb)
{
    int lo = 0, hi = n;
    while (lo < hi) {
        int m = (lo + hi) >> 1;
        if (b[m << fb] < key) lo = m + 1; else hi = m;
    }
    return lo;
}

// Segment pooling from raw h2 with affine fold; 4 graphs per 256-thread block.
__global__ __launch_bounds__(256)
void pool_k(const u32* __restrict__ h2, const int* __restrict__ batch,
            float* __restrict__ y, int layer, int nnodes, int ngraphs,
            const float* __restrict__ scale, const float* __restrict__ shift,
            const int* __restrict__ flags)
{
    int g = blockIdx.x * 4 + (threadIdx.x >> 6);
    if (g >= ngraphs) return;
    int t = threadIdx.x & 63;
    int fb = flags[1];
    int lo = lower_bound_b(batch, nnodes, g, fb);
    int hi = lower_bound_b(batch, nnodes, g + 1, fb);
    float s0 = 0.f, s1 = 0.f;
    int i = lo;
    for (; i + 4 <= hi; i += 4) {
        u32 u0 = h2[(size_t)i * 64 + t];
        u32 u1 = h2[(size_t)(i + 1) * 64 + t];
        u32 u2 = h2[(size_t)(i + 2) * 64 + t];
        u32 u3 = h2[(size_t)(i + 3) * 64 + t];
        s0 += bf_lo(u0) + bf_lo(u1) + bf_lo(u2) + bf_lo(u3);
        s1 += bf_hi(u0) + bf_hi(u1) + bf_hi(u2) + bf_hi(u3);
    }
    for (; i < hi; ++i) {
        u32 u = h2[(size_t)i * 64 + t];
        s0 += bf_lo(u);
        s1 += bf_hi(u);
    }
    float cnt = (float)(hi - lo);
    int c = t * 2;
    float* yp = &y[(size_t)g * 512 + layer * 128 + c];
    yp[0] = fmaf(s0, scale[c], shift[c] * cnt);
    yp[1] = fmaf(s1, scale[c + 1], shift[c + 1] * cnt);
}

__global__ __launch_bounds__(256)
void final_k(const float* __restrict__ a, const float* __restrict__ b,
             float* __restrict__ out, int n)
{
    int i = blockIdx.x * 256 + threadIdx.x;
    if (i < n) out[i] = a[i] + b[i];
}

extern "C" void kernel_launch(void* const* d_in, const int* in_sizes, int n_in,
                              void* d_out, int out_size, void* d_ws, size_t ws_size,
                              hipStream_t stream)
{
    const void* x       = d_in[0];
    const int*  ei      = (const int*)d_in[1];
    const int*  batch   = (const int*)d_in[2];
    const void* pre_w   = d_in[3];
    const void* pre_b   = d_in[4];
    const void* conv_w1 = d_in[5];
    const void* conv_w2 = d_in[6];
    const void* bn_g    = d_in[7];
    const void* bn_b    = d_in[8];

    const int n_nodes  = in_sizes[2];
    const int n_edges  = in_sizes[1] / 2;
    const int n_graphs = out_size / 512;
    const size_t nf = (size_t)n_nodes * 128;
    const int nsb = (n_nodes + 255) / 256;       // scan blocks
    const int NCONVB = 512;                      // persistent conv/pre grid
    const int ntiles = (n_nodes + 15) / 16;
    const int npairs = NCONVB * 2;

    float* ws      = (float*)d_ws;
    int*   flags   = (int*)ws;
    int*   bsum    = (int*)(ws + 16);
    float* scaleA  = ws + 1056;                  // [5][128]
    float* shiftA  = scaleA + 5 * 128;
    float* psum    = shiftA + 5 * 128;           // [NCONVB][128]
    float* psq     = psum + (size_t)NCONVB * 128;
    float* y       = psq + (size_t)NCONVB * 128;
    float* tA      = y  + (size_t)n_graphs * 512;
    float* tB      = tA + (size_t)n_graphs * 512;
    u32*   bufA    = (u32*)(tB + (size_t)n_graphs * 512);   // h2 buffer, bf16 [n,128]
    u32*   bufB    = bufA + nf / 2;                          // agg buffer, bf16 [n,128]
    int*   deg     = (int*)(bufB + nf / 2);
    int*   rowptr  = deg + n_nodes;
    int*   srcs    = rowptr + n_nodes + 1;
    bf16*  Wfn     = (bf16*)(((uintptr_t)(srcs + n_edges) + 15) & ~(uintptr_t)15);  // 9*16384
    bf16*  Wff     = Wfn + 9 * 16384;                        // 4*262144

    probe_k<<<1, 256, 0, stream>>>(ei, batch, (const u32*)bn_g, n_edges, n_nodes,
                                   flags, scaleA, shiftA);

    // CSR build
    hipMemsetAsync(deg, 0, n_nodes * sizeof(int), stream);
    hist_k<<<(n_edges + 255) / 256, 256, 0, stream>>>(ei, deg, n_edges, flags);
    scan1_k<<<nsb, 256, 0, stream>>>(deg, bsum, n_nodes);
    scan2_k<<<1, 1024, 0, stream>>>(bsum, nsb);
    scan3_k<<<nsb, 256, 0, stream>>>(deg, bsum, rowptr, deg, n_nodes);
    fill_k<<<(n_edges + 255) / 256, 256, 0, stream>>>(ei, deg, srcs, n_edges, flags);

    // all weight prep in one launch
    wprep_all_k<<<(1196032 + 255) / 256, 256, 0, stream>>>(
        pre_w, conv_w1, conv_w2, d_in[9], d_in[10], d_in[11], d_in[12], Wfn, flags);

    // pre: bufA = bf16(x @ pre_w + pre_b)  (persistent, weights pinned)
    pre_k<<<NCONVB, 256, 0, stream>>>(x, Wfn, pre_b, bufA, n_nodes, ntiles, npairs, flags);

    for (int l = 0; l < 4; ++l) {
        aggregate_k<<<(n_nodes + 3) / 4, 256, 0, stream>>>(
            rowptr, srcs, bufA, bufB, scaleA + l * 128, shiftA + l * 128, n_nodes);
        conv_k<<<NCONVB, 256, 0, stream>>>(bufB, Wfn + (1 + l) * 16384, Wfn + (5 + l) * 16384,
                                           bufA, psum, psq, n_nodes, ntiles, npairs);
        reduce_bn_k<<<128, 256, 0, stream>>>(psum, psq, bn_g, bn_b,
                                             scaleA + (l + 1) * 128, shiftA + (l + 1) * 128,
                                             1.f / (float)n_nodes, l, NCONVB, flags);
        pool_k<<<(n_graphs + 3) / 4, 256, 0, stream>>>(
            bufA, batch, y, l, n_nodes, n_graphs,
            scaleA + (l + 1) * 128, shiftA + (l + 1) * 128, flags);
    }

    // FF head
    const dim3 gf((n_graphs + 63) / 64, 4);
    mgemm_k<0, 0, 0><<<gf, 256, 0, stream>>>(y,  Wff + 3ull * 262144, nullptr, tB, n_graphs, 512, 512, 512, flags);
    mgemm_k<0, 1, 0><<<gf, 256, 0, stream>>>(y,  Wff + 0ull * 262144, nullptr, tA, n_graphs, 512, 512, 512, flags);
    mgemm_k<0, 1, 0><<<gf, 256, 0, stream>>>(tA, Wff + 1ull * 262144, nullptr, y,  n_graphs, 512, 512, 512, flags);
    mgemm_k<0, 1, 0><<<gf, 256, 0, stream>>>(y,  Wff + 2ull * 262144, nullptr, tA, n_graphs, 512, 512, 512, flags);

    final_k<<<(n_graphs * 512 + 255) / 256, 256, 0, stream>>>(tA, tB, (float*)d_out, n_graphs * 512);
}